// Round 13
// baseline (934.126 us; speedup 1.0000x reference)
//
#include <hip/hip_runtime.h>
#include <hip/hip_bf16.h>
#include <math.h>

#define Bq 16
#define Tq 256
#define Hq 512
#define Vq 32000
#define Gq 1536
#define NWG 16
#define LBLK 240           // consumer blocks (16+240 = 256 = 1 block/CU)
#define NBI 167            // ceil(32000/192) N-stripes

typedef __attribute__((ext_vector_type(8))) short short8;
typedef __attribute__((ext_vector_type(4))) float f32x4;
typedef __attribute__((ext_vector_type(4))) unsigned int u32x4;
typedef unsigned long long u64;

typedef const __attribute__((address_space(1))) void g_void;
typedef __attribute__((address_space(3))) void l_void;

__device__ __forceinline__ unsigned short f2bf(float f) {
    union { float f; unsigned int u; } v; v.f = f;
    unsigned int r = v.u + 0x7fffu + ((v.u >> 16) & 1u);
    return (unsigned short)(r >> 16);
}
__device__ __forceinline__ float bf2f(unsigned short h) {
    union { unsigned int u; float f; } v; v.u = ((unsigned int)h) << 16;
    return v.f;
}
__device__ __forceinline__ float sigm(float x) { return 1.0f / (1.0f + __expf(-x)); }
__device__ __forceinline__ float tanh_fast(float x) {
    float e = __expf(-2.0f * x);
    return (1.0f - e) / (1.0f + e);
}

// ---------------------------------------------------------------------------
// prep: cast E->bf16; split W_ih/W_hh into bf16 hi/lo; zero 64 consumer flags
// ---------------------------------------------------------------------------
__global__ void prep_kernel(const float* __restrict__ E, const float* __restrict__ Wih,
                            const float* __restrict__ Whh,
                            unsigned short* __restrict__ Ebf,
                            unsigned short* __restrict__ WihHi, unsigned short* __restrict__ WihLo,
                            unsigned short* __restrict__ WhhHi, unsigned short* __restrict__ WhhLo,
                            int* __restrict__ flags) {
    long tid = (long)blockIdx.x * blockDim.x + threadIdx.x;
    long stride = (long)gridDim.x * blockDim.x;
    for (long i = tid; i < (long)Vq * Hq; i += stride) Ebf[i] = f2bf(E[i]);
    for (long i = tid; i < (long)Gq * Hq; i += stride) {
        float w = Wih[i]; unsigned short hi = f2bf(w);
        WihHi[i] = hi; WihLo[i] = f2bf(w - bf2f(hi));
        w = Whh[i]; hi = f2bf(w);
        WhhHi[i] = hi; WhhLo[i] = f2bf(w - bf2f(hi));
    }
    if (tid < 2048) flags[tid] = 0;   // 64 flags spaced 128B
}

// ---------------------------------------------------------------------------
// gi: gi_all[t,b,:] = E[tok(t,b)] @ W_ih^T + b_ih   (split-bf16)
// ---------------------------------------------------------------------------
__launch_bounds__(384)
__global__ void gi_kernel(const int* __restrict__ target, const float* __restrict__ E,
                          const unsigned short* __restrict__ WihHi,
                          const unsigned short* __restrict__ WihLo,
                          const float* __restrict__ b_ih, float* __restrict__ gi_all) {
    __shared__ __align__(16) unsigned short Ahi[16][520];
    __shared__ __align__(16) unsigned short Alo[16][520];
    __shared__ int toks[16];
    int t = blockIdx.x, gb = blockIdx.y;
    int tid = threadIdx.x;
    if (tid < 16) toks[tid] = (t == 0) ? 1 : target[tid * Tq + (t - 1)];  // START=1
    __syncthreads();
    for (int idx = tid; idx < 16 * Hq; idx += 384) {
        int r = idx >> 9, k = idx & 511;
        float v = E[(long)toks[r] * Hq + k];
        unsigned short hi = f2bf(v);
        Ahi[r][k] = hi; Alo[r][k] = f2bf(v - bf2f(hi));
    }
    __syncthreads();
    int wave = tid >> 6, lane = tid & 63;
    int gcb = gb * 96 + wave * 16;
    int row = lane & 15, kg = (lane >> 4) * 8;
    const unsigned short* bh = WihHi + (long)(gcb + row) * Hq;
    const unsigned short* bl = WihLo + (long)(gcb + row) * Hq;
    f32x4 aHH = {0,0,0,0}, aHL = {0,0,0,0}, aLH = {0,0,0,0};
#pragma unroll
    for (int ks = 0; ks < 16; ++ks) {
        int k0 = ks * 32 + kg;
        short8 ah = *(const short8*)&Ahi[row][k0];
        short8 al = *(const short8*)&Alo[row][k0];
        short8 wh = *(const short8*)&bh[k0];
        short8 wl = *(const short8*)&bl[k0];
        aHH = __builtin_amdgcn_mfma_f32_16x16x32_bf16(ah, wh, aHH, 0, 0, 0);
        aHL = __builtin_amdgcn_mfma_f32_16x16x32_bf16(ah, wl, aHL, 0, 0, 0);
        aLH = __builtin_amdgcn_mfma_f32_16x16x32_bf16(al, wh, aLH, 0, 0, 0);
    }
    int g = gcb + row;
    float bi = b_ih[g];
#pragma unroll
    for (int q = 0; q < 4; ++q) {
        int b = (lane >> 4) * 4 + q;
        gi_all[((long)(t * 16 + b)) * Gq + g] = aHH[q] + aHL[q] + aLH[q] + bi;
    }
}

// ---------------------------------------------------------------------------
// fused: blocks 0..15 = rnn producers (R12-validated stamped ring, hot-spin);
// 16..255 = logits consumers with N-STRIPE OWNERSHIP: each block owns one
// 192-col E-stripe and walks m-tiles against it -> E fetched from HBM once
// (FETCH -~300MB), bursts halved via +8*(s&1) gate stagger.
// ---------------------------------------------------------------------------
__launch_bounds__(384, 1)
__global__ void fused_kernel(const float* __restrict__ h0,
                             const unsigned short* __restrict__ WhhHi,
                             const unsigned short* __restrict__ WhhLo,
                             const float* __restrict__ b_hh,
                             const float* __restrict__ gi_all,
                             unsigned int* Hpk, u64* ring,
                             int* flags,
                             const unsigned short* __restrict__ Ebf,
                             const float* __restrict__ b_out,
                             float* __restrict__ out) {
    __shared__ __align__(16) char smem[41984];
    int tid = threadIdx.x, lane = tid & 63;

    if (blockIdx.x < NWG) {
        // ================= producer =================
        __builtin_amdgcn_s_setprio(1);
        unsigned short (*Ahi)[520] = (unsigned short (*)[520])smem;
        float (*gbuf)[16][33] = (float (*)[16][33])(smem + 16640);
        int w = blockIdx.x;
        int wave = tid >> 6;
        int gate = wave >> 1;                        // 0:r 1:z 2:n
        int gcol = gate * 512 + w * 32 + (wave & 1) * 16;
        int row = lane & 15, kg = (lane >> 4) * 8;
        const unsigned short* bhp = WhhHi + (long)(gcol + row) * Hq;
        const unsigned short* blp = WhhLo + (long)(gcol + row) * Hq;
        short8 Bh[16], Bl[16];
#pragma unroll
        for (int ks = 0; ks < 16; ++ks) {
            Bh[ks] = *(const short8*)&bhp[ks * 32 + kg];
            Bl[ks] = *(const short8*)&blp[ks * 32 + kg];
        }
        float bhh = b_hh[gcol + row];
        float gin[4];
#pragma unroll
        for (int q = 0; q < 4; ++q) {
            int b = (lane >> 4) * 4 + q;
            gin[q] = gi_all[(long)b * Gq + (gcol + row)];
        }
        for (int t = 0; t < Tq; ++t) {
            // ---- acquire h_{t-1}: stamped batch poll (hot spin) ----
            if (t == 0) {
                for (int idx = tid; idx < Bq * Hq; idx += 384)
                    Ahi[idx >> 9][idx & 511] = f2bf(h0[idx]);
            } else {
                const u64* src = ring + ((t - 1) & 1) * 4096;
                u64 A0 = (u64)(src + tid);
                u64 A1 = (u64)(src + tid + 384);
                u64 A2 = (u64)(src + tid + 768);
                u64 A3 = (u64)(src + tid + 1152);
                u64 A4 = (u64)(src + tid + 1536);
                u64 A5 = (u64)(src + tid + 1920);
                u64 A6 = (u64)(src + tid + 2304);
                u64 A7 = (u64)(src + tid + 2688);
                u64 A8 = (u64)(src + tid + 3072);
                u64 A9 = (u64)(src + tid + 3456);
                u64 A10 = (u64)(src + ((tid < 256) ? (3840 + tid) : tid));
                u64 v0, v1, v2, v3, v4, v5, v6, v7, v8, v9, v10;
                unsigned int st = (unsigned int)t;
                int guard = 0;
                bool ok;
                do {
                    asm volatile(
                        "global_load_dwordx2 %0, %11, off sc0 sc1\n\t"
                        "global_load_dwordx2 %1, %12, off sc0 sc1\n\t"
                        "global_load_dwordx2 %2, %13, off sc0 sc1\n\t"
                        "global_load_dwordx2 %3, %14, off sc0 sc1\n\t"
                        "global_load_dwordx2 %4, %15, off sc0 sc1\n\t"
                        "global_load_dwordx2 %5, %16, off sc0 sc1\n\t"
                        "global_load_dwordx2 %6, %17, off sc0 sc1\n\t"
                        "global_load_dwordx2 %7, %18, off sc0 sc1\n\t"
                        "global_load_dwordx2 %8, %19, off sc0 sc1\n\t"
                        "global_load_dwordx2 %9, %20, off sc0 sc1\n\t"
                        "global_load_dwordx2 %10, %21, off sc0 sc1\n\t"
                        "s_waitcnt vmcnt(0)"
                        : "=&v"(v0), "=&v"(v1), "=&v"(v2), "=&v"(v3), "=&v"(v4),
                          "=&v"(v5), "=&v"(v6), "=&v"(v7), "=&v"(v8), "=&v"(v9),
                          "=&v"(v10)
                        : "v"(A0), "v"(A1), "v"(A2), "v"(A3), "v"(A4), "v"(A5),
                          "v"(A6), "v"(A7), "v"(A8), "v"(A9), "v"(A10)
                        : "memory");
                    bool mine = ((unsigned int)(v0 >> 32) == st) &&
                                ((unsigned int)(v1 >> 32) == st) &&
                                ((unsigned int)(v2 >> 32) == st) &&
                                ((unsigned int)(v3 >> 32) == st) &&
                                ((unsigned int)(v4 >> 32) == st) &&
                                ((unsigned int)(v5 >> 32) == st) &&
                                ((unsigned int)(v6 >> 32) == st) &&
                                ((unsigned int)(v7 >> 32) == st) &&
                                ((unsigned int)(v8 >> 32) == st) &&
                                ((unsigned int)(v9 >> 32) == st) &&
                                ((unsigned int)(v10 >> 32) == st);
                    ok = __all(mine);
                } while (!ok && ++guard < (1 << 15));   // bounded: no hangs
                {
                    int wv = tid;
                    *(unsigned int*)&Ahi[wv >> 8][(wv & 255) * 2] = (unsigned int)v0;
                    wv = tid + 384;
                    *(unsigned int*)&Ahi[wv >> 8][(wv & 255) * 2] = (unsigned int)v1;
                    wv = tid + 768;
                    *(unsigned int*)&Ahi[wv >> 8][(wv & 255) * 2] = (unsigned int)v2;
                    wv = tid + 1152;
                    *(unsigned int*)&Ahi[wv >> 8][(wv & 255) * 2] = (unsigned int)v3;
                    wv = tid + 1536;
                    *(unsigned int*)&Ahi[wv >> 8][(wv & 255) * 2] = (unsigned int)v4;
                    wv = tid + 1920;
                    *(unsigned int*)&Ahi[wv >> 8][(wv & 255) * 2] = (unsigned int)v5;
                    wv = tid + 2304;
                    *(unsigned int*)&Ahi[wv >> 8][(wv & 255) * 2] = (unsigned int)v6;
                    wv = tid + 2688;
                    *(unsigned int*)&Ahi[wv >> 8][(wv & 255) * 2] = (unsigned int)v7;
                    wv = tid + 3072;
                    *(unsigned int*)&Ahi[wv >> 8][(wv & 255) * 2] = (unsigned int)v8;
                    wv = tid + 3456;
                    *(unsigned int*)&Ahi[wv >> 8][(wv & 255) * 2] = (unsigned int)v9;
                    if (tid < 256) {
                        wv = 3840 + tid;
                        *(unsigned int*)&Ahi[wv >> 8][(wv & 255) * 2] = (unsigned int)v10;
                    }
                }
            }
            __syncthreads();   // (A) Ahi ready — also block-joins prev step
            // ---- gh = h(bf16) @ Whh^T: 2 products, 4 chains ----
            f32x4 xH = {0,0,0,0}, xL = {0,0,0,0};
            f32x4 yH = {0,0,0,0}, yL = {0,0,0,0};
#pragma unroll
            for (int ks = 0; ks < 8; ++ks) {
                short8 ah = *(const short8*)&Ahi[row][ks * 32 + kg];
                xH = __builtin_amdgcn_mfma_f32_16x16x32_bf16(ah, Bh[ks], xH, 0, 0, 0);
                xL = __builtin_amdgcn_mfma_f32_16x16x32_bf16(ah, Bl[ks], xL, 0, 0, 0);
            }
#pragma unroll
            for (int ks = 8; ks < 16; ++ks) {
                short8 ah = *(const short8*)&Ahi[row][ks * 32 + kg];
                yH = __builtin_amdgcn_mfma_f32_16x16x32_bf16(ah, Bh[ks], yH, 0, 0, 0);
                yL = __builtin_amdgcn_mfma_f32_16x16x32_bf16(ah, Bl[ks], yL, 0, 0, 0);
            }
            int jj = (wave & 1) * 16 + row;
#pragma unroll
            for (int q = 0; q < 4; ++q) {
                int b = (lane >> 4) * 4 + q;
                float ghv = (xH[q] + yH[q]) + (xL[q] + yL[q]) + bhh;
                if (gate < 2) gbuf[gate][b][jj] = ghv + gin[q];
                else { gbuf[2][b][jj] = gin[q]; gbuf[3][b][jj] = ghv; }
            }
            __syncthreads();   // (B) gbuf ready
            // ---- gates + h_new; stamped ring store (no drain, no flag) ----
            if (tid < 256) {
                int b = tid >> 4, jp = tid & 15;
                int j0 = jp * 2, j1 = j0 + 1;
                int jc0 = w * 32 + j0;
                float r0 = sigm(gbuf[0][b][j0]);
                float z0 = sigm(gbuf[1][b][j0]);
                float n0 = tanh_fast(gbuf[2][b][j0] + r0 * gbuf[3][b][j0]);
                float hn0 = (1.0f - z0) * n0 + z0 * bf2f(Ahi[b][jc0]);
                float r1 = sigm(gbuf[0][b][j1]);
                float z1 = sigm(gbuf[1][b][j1]);
                float n1 = tanh_fast(gbuf[2][b][j1] + r1 * gbuf[3][b][j1]);
                float hn1 = (1.0f - z1) * n1 + z1 * bf2f(Ahi[b][jc0 + 1]);
                unsigned int pk = (unsigned int)f2bf(hn0) |
                                  ((unsigned int)f2bf(hn1) << 16);
                long idx = b * 256 + w * 16 + jp;
                u64 word = ((u64)(unsigned int)(t + 1) << 32) | pk;
                __hip_atomic_store(&ring[(t & 1) * 4096 + idx], word,
                                   __ATOMIC_RELAXED, __HIP_MEMORY_SCOPE_AGENT);
                __hip_atomic_store(&Hpk[(long)t * 4096 + idx], pk,
                                   __ATOMIC_RELAXED, __HIP_MEMORY_SCOPE_AGENT);
                if ((t & 7) == 7) {   // lagged consumer publication (off path)
                    asm volatile("s_waitcnt vmcnt(0)" ::: "memory");
                    if (lane == 0)
                        __hip_atomic_store(&flags[(w * 4 + wave) * 32], t + 1,
                                           __ATOMIC_RELAXED, __HIP_MEMORY_SCOPE_AGENT);
                }
            }
            // gi prefetch for t+1 (off critical path)
            int tp = (t + 1 < Tq) ? (t + 1) : t;
#pragma unroll
            for (int q = 0; q < 4; ++q) {
                int b = (lane >> 4) * 4 + q;
                gin[q] = gi_all[((long)(tp * 16 + b)) * Gq + (gcol + row)];
            }
            // no end barrier: next-step stamp poll + barrier (A) cover reuse
        }
    } else {
        // ============ consumer: n-stripe ownership, m-walk ============
        unsigned short* As = (unsigned short*)smem;              // 128x64
        unsigned short* Bs = As + 128 * 64;                      // 192x64
        int j = blockIdx.x - NWG;                                // 0..239
        int s = (j < NBI) ? j : (j - NBI);                       // stripe
        int mlo = 0, mhi = 32;
        if (s < 73) { if (j < NBI) mhi = 16; else mlo = 16; }    // co-owned split
        int n0 = s * 192;
        int d8 = 8 * (s & 1);                                    // burst stagger
        int wid = tid >> 6;
        int wr = wid & 1, wc = wid >> 1;                         // 2x3 wave grid
        int fr = lane & 15, r7 = lane & 7, sb = lane >> 4;
        int rA = lane >> 3, slp = (lane & 7) ^ rA;               // B pre-swizzle
        for (int mt = mlo; mt < mhi; ++mt) {
            int m0 = mt * 128;
            if (tid < 64) {
                int need = (mt + 1) * 8 + d8;
                if (need > 256) need = 256;
                int guard = 0;
                while (guard < (1 << 18)) {
                    int fv = __hip_atomic_load(&flags[lane * 32], __ATOMIC_RELAXED,
                                               __HIP_MEMORY_SCOPE_AGENT);
                    if (__all(fv >= need)) break;
                    __builtin_amdgcn_s_sleep(127);
                    ++guard;
                }
            }
            __syncthreads();   // gate + LDS reuse guard
            f32x4 acc[4][4] = {};
            const unsigned int* srcA = Hpk + (long)(mt * 8) * 4096;
            for (int kt = 0; kt < 8; ++kt) {
                if (kt) __syncthreads();
                int ko = kt * 64;
#pragma unroll
                for (int i = 0; i < 4; ++i) {
                    int brow = n0 + wid * 8 + i * 48 + rA;
                    if (brow > Vq - 1) brow = Vq - 1;
                    __builtin_amdgcn_global_load_lds(
                        (g_void*)(Ebf + (long)brow * Hq + ko + slp * 8),
                        (l_void*)(Bs + (wid * 8 + i * 48) * 64), 16, 0, 0);
                }
                for (int c = tid; c < 1024; c += 384) {
                    int r = c >> 3, g8 = c & 7;
                    u32x4 v = *(const u32x4*)&srcA[(long)(r >> 4) * 4096 +
                                                   (r & 15) * 256 + kt * 32 + g8 * 4];
                    *(u32x4*)&As[r * 64 + ((g8 ^ (r & 7)) << 3)] = v;
                }
                __syncthreads();
#pragma unroll
                for (int ks = 0; ks < 2; ++ks) {
                    short8 af[4], bfr[4];
#pragma unroll
                    for (int f = 0; f < 4; ++f) {
                        af[f]  = *(const short8*)&As[(wr * 64 + f * 16 + fr) * 64 +
                                                     (((sb + ks * 4) ^ r7) << 3)];
                        bfr[f] = *(const short8*)&Bs[(wc * 64 + f * 16 + fr) * 64 +
                                                     (((sb + ks * 4) ^ r7) << 3)];
                    }
#pragma unroll
                    for (int fm = 0; fm < 4; ++fm)
#pragma unroll
                        for (int fn = 0; fn < 4; ++fn)
                            acc[fm][fn] = __builtin_amdgcn_mfma_f32_16x16x32_bf16(
                                af[fm], bfr[fn], acc[fm][fn], 0, 0, 0);
                }
            }
#pragma unroll
            for (int fn = 0; fn < 4; ++fn) {
                int v = n0 + wc * 64 + fn * 16 + fr;
                if (v < Vq) {
                    float bo = b_out[v];
#pragma unroll
                    for (int fm = 0; fm < 4; ++fm) {
#pragma unroll
                        for (int q = 0; q < 4; ++q) {
                            int m = m0 + wr * 64 + fm * 16 + (lane >> 4) * 4 + q;
                            out[((long)(m & 15) * Tq + (m >> 4)) * Vq + v] =
                                acc[fm][fn][q] + bo;
                        }
                    }
                }
            }
        }
    }
}

// ---------------------------------------------------------------------------
extern "C" void kernel_launch(void* const* d_in, const int* in_sizes, int n_in,
                              void* d_out, int out_size, void* d_ws, size_t ws_size,
                              hipStream_t stream) {
    const float* h0    = (const float*)d_in[0];
    const int*   target= (const int*)d_in[1];
    const float* E     = (const float*)d_in[2];
    const float* Wih   = (const float*)d_in[3];
    const float* Whh   = (const float*)d_in[4];
    const float* b_ih  = (const float*)d_in[5];
    const float* b_hh  = (const float*)d_in[6];
    const float* b_out = (const float*)d_in[7];
    float* out = (float*)d_out;

    char* ws = (char*)d_ws;
    size_t off = 0;
    unsigned short* Ebf   = (unsigned short*)(ws + off); off += (size_t)Vq * Hq * 2;
    unsigned short* WihHi = (unsigned short*)(ws + off); off += (size_t)Gq * Hq * 2;
    unsigned short* WihLo = (unsigned short*)(ws + off); off += (size_t)Gq * Hq * 2;
    unsigned short* WhhHi = (unsigned short*)(ws + off); off += (size_t)Gq * Hq * 2;
    unsigned short* WhhLo = (unsigned short*)(ws + off); off += (size_t)Gq * Hq * 2;
    float*          gi_all= (float*)(ws + off);          off += (size_t)Tq * Bq * Gq * 4;
    unsigned int*   Hpk   = (unsigned int*)(ws + off);   off += (size_t)Tq * 4096 * 4;
    u64*            ring  = (u64*)(ws + off);            off += (size_t)2 * 4096 * 8;
    int*            flags = (int*)(ws + off);            off += 2048 * 4;

    prep_kernel<<<dim3(2048), dim3(256), 0, stream>>>(E, Wih, Whh, Ebf, WihHi, WihLo,
                                                      WhhHi, WhhLo, flags);
    gi_kernel<<<dim3(Tq, 16), dim3(384), 0, stream>>>(target, E, WihHi, WihLo, b_ih, gi_all);
    fused_kernel<<<dim3(256), dim3(384), 0, stream>>>(h0, WhhHi, WhhLo, b_hh, gi_all,
                                                      Hpk, ring, flags, Ebf, b_out, out);
}

// Round 14
// 871.444 us; speedup vs baseline: 1.0719x; 1.0719x over previous
//
#include <hip/hip_runtime.h>
#include <hip/hip_bf16.h>
#include <math.h>

#define Bq 16
#define Tq 256
#define Hq 512
#define Vq 32000
#define Gq 1536
#define NWG 16
#define CONS 240           // consumer blocks (16+240 = 256 = 1 block/CU)
#define NBI 167            // ceil(32000/192) N-stripes

typedef __attribute__((ext_vector_type(8))) short short8;
typedef __attribute__((ext_vector_type(4))) float f32x4;
typedef __attribute__((ext_vector_type(4))) unsigned int u32x4;
typedef unsigned long long u64;

typedef const __attribute__((address_space(1))) void g_void;
typedef __attribute__((address_space(3))) void l_void;

__device__ __forceinline__ unsigned short f2bf(float f) {
    union { float f; unsigned int u; } v; v.f = f;
    unsigned int r = v.u + 0x7fffu + ((v.u >> 16) & 1u);
    return (unsigned short)(r >> 16);
}
__device__ __forceinline__ float bf2f(unsigned short h) {
    union { unsigned int u; float f; } v; v.u = ((unsigned int)h) << 16;
    return v.f;
}
__device__ __forceinline__ float sigm(float x) { return 1.0f / (1.0f + __expf(-x)); }
__device__ __forceinline__ float tanh_fast(float x) {
    float e = __expf(-2.0f * x);
    return (1.0f - e) / (1.0f + e);
}

// ---------------------------------------------------------------------------
// tiny: zero control words (flags + gicol). Poison 0xAA.. is negative -> all
// polls wait; zeroing makes first-call sync honest and replay-safe.
// ---------------------------------------------------------------------------
__global__ void zero_kernel(int* __restrict__ flags, int* __restrict__ gicol) {
    int tid = threadIdx.x;
    for (int i = tid; i < 2048; i += 384) flags[i] = 0;
    for (int i = tid; i < 256; i += 384) gicol[i] = 0;
}

// ---------------------------------------------------------------------------
// mega: blocks 0..15 producers (GRU ring, R12-validated step; Whh split
// in-register at init). Blocks 16..255 consumers: (A) gi items -> gi_all +
// gicol counters; (B) self-cast own E-stripe; (C) stripe-owned logits m-walk.
// ---------------------------------------------------------------------------
__launch_bounds__(384, 1)
__global__ void mega_kernel(const float* __restrict__ h0,
                            const int* __restrict__ target,
                            const float* __restrict__ E,
                            const float* __restrict__ Wih,
                            const float* __restrict__ Whh,
                            const float* __restrict__ b_ih,
                            const float* __restrict__ b_hh,
                            const float* __restrict__ b_out,
                            float* gi_all,
                            unsigned int* Hpk, u64* ring,
                            int* flags, int* gicol,
                            unsigned short* __restrict__ Ebf,
                            float* __restrict__ out) {
    __shared__ __align__(16) char smem[41984];
    int tid = threadIdx.x, lane = tid & 63;

    if (blockIdx.x < NWG) {
        // ================= producer =================
        __builtin_amdgcn_s_setprio(1);
        unsigned short (*Ahi)[520] = (unsigned short (*)[520])smem;
        float (*gbuf)[16][33] = (float (*)[16][33])(smem + 16640);
        int w = blockIdx.x;
        int wave = tid >> 6;
        int gate = wave >> 1;                        // 0:r 1:z 2:n
        int gcol = gate * 512 + w * 32 + (wave & 1) * 16;
        int row = lane & 15, kg = (lane >> 4) * 8;
        // ---- split own Whh slice f32 -> bf16 hi/lo registers (was prep) ----
        const float* whp = Whh + (long)(gcol + row) * Hq;
        short8 Bh[16], Bl[16];
#pragma unroll
        for (int ks = 0; ks < 16; ++ks) {
            f32x4 a = *(const f32x4*)&whp[ks * 32 + kg];
            f32x4 c = *(const f32x4*)&whp[ks * 32 + kg + 4];
#pragma unroll
            for (int e = 0; e < 4; ++e) {
                unsigned short hi = f2bf(a[e]);
                Bh[ks][e] = (short)hi; Bl[ks][e] = (short)f2bf(a[e] - bf2f(hi));
                hi = f2bf(c[e]);
                Bh[ks][e + 4] = (short)hi; Bl[ks][e + 4] = (short)f2bf(c[e] - bf2f(hi));
            }
        }
        float bhh = b_hh[gcol + row];
        // ---- wait for gi columns 0,1 (consumers produce them in ~5us) ----
        {
            int guard = 0;
            while (guard < (1 << 20)) {
                int g0 = __hip_atomic_load(&gicol[0], __ATOMIC_RELAXED,
                                           __HIP_MEMORY_SCOPE_AGENT);
                int g1 = __hip_atomic_load(&gicol[1], __ATOMIC_RELAXED,
                                           __HIP_MEMORY_SCOPE_AGENT);
                if (g0 >= 16 && g1 >= 16) break;
                __builtin_amdgcn_s_sleep(8);
                ++guard;
            }
        }
        float gin[4];
#pragma unroll
        for (int q = 0; q < 4; ++q) {
            int b = (lane >> 4) * 4 + q;
            gin[q] = gi_all[(long)b * Gq + (gcol + row)];
        }
        for (int t = 0; t < Tq; ++t) {
            // ---- acquire h_{t-1}: stamped batch poll + gi gate (12 loads) ----
            if (t == 0) {
                for (int idx = tid; idx < Bq * Hq; idx += 384)
                    Ahi[idx >> 9][idx & 511] = f2bf(h0[idx]);
            } else {
                const u64* src = ring + ((t - 1) & 1) * 4096;
                u64 A0 = (u64)(src + tid);
                u64 A1 = (u64)(src + tid + 384);
                u64 A2 = (u64)(src + tid + 768);
                u64 A3 = (u64)(src + tid + 1152);
                u64 A4 = (u64)(src + tid + 1536);
                u64 A5 = (u64)(src + tid + 1920);
                u64 A6 = (u64)(src + tid + 2304);
                u64 A7 = (u64)(src + tid + 2688);
                u64 A8 = (u64)(src + tid + 3072);
                u64 A9 = (u64)(src + tid + 3456);
                u64 A10 = (u64)(src + ((tid < 256) ? (3840 + tid) : tid));
                int tc = (t + 1 < Tq) ? (t + 1) : (Tq - 1);
                u64 A11 = (u64)(gicol + tc);
                u64 v0, v1, v2, v3, v4, v5, v6, v7, v8, v9, v10;
                unsigned int g11;
                unsigned int st = (unsigned int)t;
                int guard = 0;
                bool ok;
                do {
                    asm volatile(
                        "global_load_dwordx2 %0, %12, off sc0 sc1\n\t"
                        "global_load_dwordx2 %1, %13, off sc0 sc1\n\t"
                        "global_load_dwordx2 %2, %14, off sc0 sc1\n\t"
                        "global_load_dwordx2 %3, %15, off sc0 sc1\n\t"
                        "global_load_dwordx2 %4, %16, off sc0 sc1\n\t"
                        "global_load_dwordx2 %5, %17, off sc0 sc1\n\t"
                        "global_load_dwordx2 %6, %18, off sc0 sc1\n\t"
                        "global_load_dwordx2 %7, %19, off sc0 sc1\n\t"
                        "global_load_dwordx2 %8, %20, off sc0 sc1\n\t"
                        "global_load_dwordx2 %9, %21, off sc0 sc1\n\t"
                        "global_load_dwordx2 %10, %22, off sc0 sc1\n\t"
                        "global_load_dword %11, %23, off sc0 sc1\n\t"
                        "s_waitcnt vmcnt(0)"
                        : "=&v"(v0), "=&v"(v1), "=&v"(v2), "=&v"(v3), "=&v"(v4),
                          "=&v"(v5), "=&v"(v6), "=&v"(v7), "=&v"(v8), "=&v"(v9),
                          "=&v"(v10), "=&v"(g11)
                        : "v"(A0), "v"(A1), "v"(A2), "v"(A3), "v"(A4), "v"(A5),
                          "v"(A6), "v"(A7), "v"(A8), "v"(A9), "v"(A10), "v"(A11)
                        : "memory");
                    bool mine = ((unsigned int)(v0 >> 32) == st) &&
                                ((unsigned int)(v1 >> 32) == st) &&
                                ((unsigned int)(v2 >> 32) == st) &&
                                ((unsigned int)(v3 >> 32) == st) &&
                                ((unsigned int)(v4 >> 32) == st) &&
                                ((unsigned int)(v5 >> 32) == st) &&
                                ((unsigned int)(v6 >> 32) == st) &&
                                ((unsigned int)(v7 >> 32) == st) &&
                                ((unsigned int)(v8 >> 32) == st) &&
                                ((unsigned int)(v9 >> 32) == st) &&
                                ((unsigned int)(v10 >> 32) == st) &&
                                ((int)g11 >= 16);
                    ok = __all(mine);
                    if (!ok) __builtin_amdgcn_s_sleep(1);
                } while (!ok && ++guard < (1 << 15));   // bounded: no hangs
                {
                    int wv = tid;
                    *(unsigned int*)&Ahi[wv >> 8][(wv & 255) * 2] = (unsigned int)v0;
                    wv = tid + 384;
                    *(unsigned int*)&Ahi[wv >> 8][(wv & 255) * 2] = (unsigned int)v1;
                    wv = tid + 768;
                    *(unsigned int*)&Ahi[wv >> 8][(wv & 255) * 2] = (unsigned int)v2;
                    wv = tid + 1152;
                    *(unsigned int*)&Ahi[wv >> 8][(wv & 255) * 2] = (unsigned int)v3;
                    wv = tid + 1536;
                    *(unsigned int*)&Ahi[wv >> 8][(wv & 255) * 2] = (unsigned int)v4;
                    wv = tid + 1920;
                    *(unsigned int*)&Ahi[wv >> 8][(wv & 255) * 2] = (unsigned int)v5;
                    wv = tid + 2304;
                    *(unsigned int*)&Ahi[wv >> 8][(wv & 255) * 2] = (unsigned int)v6;
                    wv = tid + 2688;
                    *(unsigned int*)&Ahi[wv >> 8][(wv & 255) * 2] = (unsigned int)v7;
                    wv = tid + 3072;
                    *(unsigned int*)&Ahi[wv >> 8][(wv & 255) * 2] = (unsigned int)v8;
                    wv = tid + 3456;
                    *(unsigned int*)&Ahi[wv >> 8][(wv & 255) * 2] = (unsigned int)v9;
                    if (tid < 256) {
                        wv = 3840 + tid;
                        *(unsigned int*)&Ahi[wv >> 8][(wv & 255) * 2] = (unsigned int)v10;
                    }
                }
            }
            __syncthreads();   // (A) Ahi ready
            f32x4 xH = {0,0,0,0}, xL = {0,0,0,0};
            f32x4 yH = {0,0,0,0}, yL = {0,0,0,0};
#pragma unroll
            for (int ks = 0; ks < 8; ++ks) {
                short8 ah = *(const short8*)&Ahi[row][ks * 32 + kg];
                xH = __builtin_amdgcn_mfma_f32_16x16x32_bf16(ah, Bh[ks], xH, 0, 0, 0);
                xL = __builtin_amdgcn_mfma_f32_16x16x32_bf16(ah, Bl[ks], xL, 0, 0, 0);
            }
#pragma unroll
            for (int ks = 8; ks < 16; ++ks) {
                short8 ah = *(const short8*)&Ahi[row][ks * 32 + kg];
                yH = __builtin_amdgcn_mfma_f32_16x16x32_bf16(ah, Bh[ks], yH, 0, 0, 0);
                yL = __builtin_amdgcn_mfma_f32_16x16x32_bf16(ah, Bl[ks], yL, 0, 0, 0);
            }
            int jj = (wave & 1) * 16 + row;
#pragma unroll
            for (int q = 0; q < 4; ++q) {
                int b = (lane >> 4) * 4 + q;
                float ghv = (xH[q] + yH[q]) + (xL[q] + yL[q]) + bhh;
                if (gate < 2) gbuf[gate][b][jj] = ghv + gin[q];
                else { gbuf[2][b][jj] = gin[q]; gbuf[3][b][jj] = ghv; }
            }
            __syncthreads();   // (B) gbuf ready
            if (tid < 256) {
                int b = tid >> 4, jp = tid & 15;
                int j0 = jp * 2, j1 = j0 + 1;
                int jc0 = w * 32 + j0;
                float r0 = sigm(gbuf[0][b][j0]);
                float z0 = sigm(gbuf[1][b][j0]);
                float n0 = tanh_fast(gbuf[2][b][j0] + r0 * gbuf[3][b][j0]);
                float hn0 = (1.0f - z0) * n0 + z0 * bf2f(Ahi[b][jc0]);
                float r1 = sigm(gbuf[0][b][j1]);
                float z1 = sigm(gbuf[1][b][j1]);
                float n1 = tanh_fast(gbuf[2][b][j1] + r1 * gbuf[3][b][j1]);
                float hn1 = (1.0f - z1) * n1 + z1 * bf2f(Ahi[b][jc0 + 1]);
                unsigned int pk = (unsigned int)f2bf(hn0) |
                                  ((unsigned int)f2bf(hn1) << 16);
                long idx = b * 256 + w * 16 + jp;
                u64 word = ((u64)(unsigned int)(t + 1) << 32) | pk;
                __hip_atomic_store(&ring[(t & 1) * 4096 + idx], word,
                                   __ATOMIC_RELAXED, __HIP_MEMORY_SCOPE_AGENT);
                __hip_atomic_store(&Hpk[(long)t * 4096 + idx], pk,
                                   __ATOMIC_RELAXED, __HIP_MEMORY_SCOPE_AGENT);
                if ((t & 7) == 7) {   // lagged consumer publication (off path)
                    asm volatile("s_waitcnt vmcnt(0)" ::: "memory");
                    if (lane == 0)
                        __hip_atomic_store(&flags[(w * 4 + wave) * 32], t + 1,
                                           __ATOMIC_RELAXED, __HIP_MEMORY_SCOPE_AGENT);
                }
            }
            int tp = (t + 1 < Tq) ? (t + 1) : t;
#pragma unroll
            for (int q = 0; q < 4; ++q) {
                int b = (lane >> 4) * 4 + q;
                gin[q] = gi_all[((long)(tp * 16 + b)) * Gq + (gcol + row)];
            }
        }
    } else {
        int j = blockIdx.x - NWG;                                // 0..239
        int wave = tid >> 6;
        int row = lane & 15, kg = (lane >> 4) * 8;
        // ============ Phase A: gi items (was gi_kernel) ============
        {
            unsigned short (*Ahi)[520] = (unsigned short (*)[520])smem;
            unsigned short (*Alo)[520] = (unsigned short (*)[520])(smem + 16640);
            int* toks = (int*)(smem + 33280);
            for (int item = j; item < 4096; item += CONS) {
                int t = item >> 4, gb = item & 15;
                __syncthreads();   // LDS reuse guard
                if (tid < 16) toks[tid] = (t == 0) ? 1 : target[tid * Tq + (t - 1)];
                __syncthreads();
                for (int idx = tid; idx < 16 * Hq; idx += 384) {
                    int r = idx >> 9, k = idx & 511;
                    float v = E[(long)toks[r] * Hq + k];
                    unsigned short hi = f2bf(v);
                    Ahi[r][k] = hi; Alo[r][k] = f2bf(v - bf2f(hi));
                }
                __syncthreads();
                int gcb = gb * 96 + wave * 16;
                const float* wrow = Wih + (long)(gcb + row) * Hq;
                f32x4 aHH = {0,0,0,0}, aHL = {0,0,0,0}, aLH = {0,0,0,0};
#pragma unroll
                for (int ks = 0; ks < 16; ++ks) {
                    int k0 = ks * 32 + kg;
                    short8 ah = *(const short8*)&Ahi[row][k0];
                    short8 al = *(const short8*)&Alo[row][k0];
                    f32x4 wa = *(const f32x4*)&wrow[k0];
                    f32x4 wb = *(const f32x4*)&wrow[k0 + 4];
                    short8 wh, wl;
#pragma unroll
                    for (int e = 0; e < 4; ++e) {
                        unsigned short hi = f2bf(wa[e]);
                        wh[e] = (short)hi; wl[e] = (short)f2bf(wa[e] - bf2f(hi));
                        hi = f2bf(wb[e]);
                        wh[e + 4] = (short)hi; wl[e + 4] = (short)f2bf(wb[e] - bf2f(hi));
                    }
                    aHH = __builtin_amdgcn_mfma_f32_16x16x32_bf16(ah, wh, aHH, 0, 0, 0);
                    aHL = __builtin_amdgcn_mfma_f32_16x16x32_bf16(ah, wl, aHL, 0, 0, 0);
                    aLH = __builtin_amdgcn_mfma_f32_16x16x32_bf16(al, wh, aLH, 0, 0, 0);
                }
                int g = gcb + row;
                float bi = b_ih[g];
#pragma unroll
                for (int q = 0; q < 4; ++q) {
                    int b = (lane >> 4) * 4 + q;
                    __hip_atomic_store(&gi_all[((long)(t * 16 + b)) * Gq + g],
                                       aHH[q] + aHL[q] + aLH[q] + bi,
                                       __ATOMIC_RELAXED, __HIP_MEMORY_SCOPE_AGENT);
                }
                __syncthreads();   // per-wave vmcnt drain before counter bump
                if (tid == 0)
                    __hip_atomic_fetch_add(&gicol[t], 1, __ATOMIC_RELAXED,
                                           __HIP_MEMORY_SCOPE_AGENT);
            }
        }
        // ============ Phase B: self-cast own E-stripe (was prep) ============
        int s = (j < NBI) ? j : (j - NBI);                       // stripe
        int n0 = s * 192;
        int nend = (n0 + 192 < Vq) ? (n0 + 192) : Vq;
        {
            long base = (long)n0 * Hq;
            long elems = (long)(nend - n0) * Hq;
            for (long k = (long)tid * 4; k < elems; k += 384 * 4) {
                f32x4 v = *(const f32x4*)&E[base + k];
                unsigned short o0 = f2bf(v[0]), o1 = f2bf(v[1]);
                unsigned short o2 = f2bf(v[2]), o3 = f2bf(v[3]);
                *(u64*)&Ebf[base + k] = (u64)o0 | ((u64)o1 << 16) |
                                        ((u64)o2 << 32) | ((u64)o3 << 48);
            }
        }
        // ============ Phase C: stripe-owned logits m-walk ============
        unsigned short* As = (unsigned short*)smem;              // 128x64
        unsigned short* Bs = As + 128 * 64;                      // 192x64
        int mlo = 0, mhi = 32;
        if (s < 73) { if (j < NBI) mhi = 16; else mlo = 16; }
        int wid = tid >> 6;
        int wr = wid & 1, wc = wid >> 1;                         // 2x3 wave grid
        int fr = lane & 15, r7 = lane & 7, sb = lane >> 4;
        int rA = lane >> 3, slp = (lane & 7) ^ rA;               // B pre-swizzle
        for (int mt = mlo; mt < mhi; ++mt) {
            int m0 = mt * 128;
            if (tid < 64) {
                int need = (mt + 1) * 8;
                int guard = 0;
                while (guard < (1 << 18)) {
                    int fv = __hip_atomic_load(&flags[lane * 32], __ATOMIC_RELAXED,
                                               __HIP_MEMORY_SCOPE_AGENT);
                    if (__all(fv >= need)) break;
                    __builtin_amdgcn_s_sleep(127);
                    ++guard;
                }
            }
            __syncthreads();   // gate + LDS reuse guard
            f32x4 acc[4][4] = {};
            const unsigned int* srcA = Hpk + (long)(mt * 8) * 4096;
            for (int kt = 0; kt < 8; ++kt) {
                if (kt) __syncthreads();
                int ko = kt * 64;
#pragma unroll
                for (int i = 0; i < 4; ++i) {
                    int brow = n0 + wid * 8 + i * 48 + rA;
                    if (brow > Vq - 1) brow = Vq - 1;
                    __builtin_amdgcn_global_load_lds(
                        (g_void*)(Ebf + (long)brow * Hq + ko + slp * 8),
                        (l_void*)(Bs + (wid * 8 + i * 48) * 64), 16, 0, 0);
                }
                for (int c = tid; c < 1024; c += 384) {
                    int r = c >> 3, g8 = c & 7;
                    u32x4 v = *(const u32x4*)&srcA[(long)(r >> 4) * 4096 +
                                                   (r & 15) * 256 + kt * 32 + g8 * 4];
                    *(u32x4*)&As[r * 64 + ((g8 ^ (r & 7)) << 3)] = v;
                }
                __syncthreads();
#pragma unroll
                for (int ks = 0; ks < 2; ++ks) {
                    short8 af[4], bfr[4];
#pragma unroll
                    for (int f = 0; f < 4; ++f) {
                        af[f]  = *(const short8*)&As[(wr * 64 + f * 16 + fr) * 64 +
                                                     (((sb + ks * 4) ^ r7) << 3)];
                        bfr[f] = *(const short8*)&Bs[(wc * 64 + f * 16 + fr) * 64 +
                                                     (((sb + ks * 4) ^ r7) << 3)];
                    }
#pragma unroll
                    for (int fm = 0; fm < 4; ++fm)
#pragma unroll
                        for (int fn = 0; fn < 4; ++fn)
                            acc[fm][fn] = __builtin_amdgcn_mfma_f32_16x16x32_bf16(
                                af[fm], bfr[fn], acc[fm][fn], 0, 0, 0);
                }
            }
#pragma unroll
            for (int fn = 0; fn < 4; ++fn) {
                int v = n0 + wc * 64 + fn * 16 + fr;
                if (v < Vq) {
                    float bo = b_out[v];
#pragma unroll
                    for (int fm = 0; fm < 4; ++fm) {
#pragma unroll
                        for (int q = 0; q < 4; ++q) {
                            int m = m0 + wr * 64 + fm * 16 + (lane >> 4) * 4 + q;
                            out[((long)(m & 15) * Tq + (m >> 4)) * Vq + v] =
                                acc[fm][fn][q] + bo;
                        }
                    }
                }
            }
        }
    }
}

// ---------------------------------------------------------------------------
extern "C" void kernel_launch(void* const* d_in, const int* in_sizes, int n_in,
                              void* d_out, int out_size, void* d_ws, size_t ws_size,
                              hipStream_t stream) {
    const float* h0    = (const float*)d_in[0];
    const int*   target= (const int*)d_in[1];
    const float* E     = (const float*)d_in[2];
    const float* Wih   = (const float*)d_in[3];
    const float* Whh   = (const float*)d_in[4];
    const float* b_ih  = (const float*)d_in[5];
    const float* b_hh  = (const float*)d_in[6];
    const float* b_out = (const float*)d_in[7];
    float* out = (float*)d_out;

    char* ws = (char*)d_ws;
    size_t off = 0;
    unsigned short* Ebf   = (unsigned short*)(ws + off); off += (size_t)Vq * Hq * 2;
    float*          gi_all= (float*)(ws + off);          off += (size_t)Tq * Bq * Gq * 4;
    unsigned int*   Hpk   = (unsigned int*)(ws + off);   off += (size_t)Tq * 4096 * 4;
    u64*            ring  = (u64*)(ws + off);            off += (size_t)2 * 4096 * 8;
    int*            flags = (int*)(ws + off);            off += 2048 * 4;
    int*            gicol = (int*)(ws + off);            off += 256 * 4;

    zero_kernel<<<dim3(1), dim3(384), 0, stream>>>(flags, gicol);
    mega_kernel<<<dim3(256), dim3(384), 0, stream>>>(h0, target, E, Wih, Whh, b_ih,
                                                     b_hh, b_out, gi_all, Hpk, ring,
                                                     flags, gicol, Ebf, out);
}